// Round 16
// baseline (437.485 us; speedup 1.0000x reference)
//
#include <hip/hip_runtime.h>

typedef __attribute__((ext_vector_type(4))) float  f32x4;
typedef __attribute__((ext_vector_type(8))) __bf16 bf16x8;
typedef __attribute__((ext_vector_type(4))) __bf16 bf16x4;

// ---------------------------------------------------------------------------
// prep: weight packing + bias concat + CPB table, one launch (147 blocks).
// Blocks [0,131): i = bid*256+tid covers
//   [0, 24576)        W2 packed qkv weights (head, ft, ks, lane fragment order)
//   [24576, 32768)    Wp packed proj weights (oc-group, ft, ks, lane)
//   [32768, 33536)    bcat = concat(q_bias, 0, v_bias) f32[768]
// Blocks [131, 147): CPB table cpbias[8][64][64] f32 (4096 (l,m) pairs)
// ---------------------------------------------------------------------------
__global__ __launch_bounds__(256) void prep_kernel(
    const float* __restrict__ qw, const float* __restrict__ pw,
    const float* __restrict__ qb, const float* __restrict__ vb,
    const float* __restrict__ w1, const float* __restrict__ b1,
    const float* __restrict__ w2,
    __bf16* __restrict__ W2, __bf16* __restrict__ Wp,
    float* __restrict__ bcat, float* __restrict__ cpbias)
{
  if (blockIdx.x < 131) {
    int i = blockIdx.x * 256 + threadIdx.x;
    if (i < 24576) {                       // 8 heads * 6 ft * 8 ks * 64 lanes
      int h = i / 3072, rem = i - h * 3072;
      int ft = rem >> 9, rem2 = rem & 511;
      int ks = rem2 >> 6, l = rem2 & 63;
      int g = l >> 4, c = l & 15;
      int col = h * 96 + ft * 16 + c;
      bf16x8 v;
      #pragma unroll
      for (int j = 0; j < 8; ++j)
        v[j] = (__bf16)qw[(ks * 32 + g * 8 + j) * 768 + col];
      *(bf16x8*)(W2 + (size_t)i * 8) = v;
    } else if (i < 24576 + 8192) {         // 8 oc-groups * 2 ft * 8 ks * 64 lanes
      int j = i - 24576;
      int wv = j >> 10, rem = j & 1023;
      int ft = rem >> 9, rem2 = rem & 511;
      int ks = rem2 >> 6, l = rem2 & 63;
      int g = l >> 4, c = l & 15;
      int col = wv * 32 + ft * 16 + c;
      bf16x8 v;
      #pragma unroll
      for (int j8 = 0; j8 < 8; ++j8)
        v[j8] = (__bf16)pw[(ks * 32 + g * 8 + j8) * 256 + col];
      *(bf16x8*)(Wp + (size_t)j * 8) = v;
    } else if (i < 24576 + 8192 + 768) {
      int cdx = i - 24576 - 8192;
      bcat[cdx] = (cdx < 256) ? qb[cdx] : ((cdx < 512) ? 0.0f : vb[cdx - 512]);
    }
  } else {
    int pair = (blockIdx.x - 131) * 256 + threadIdx.x;   // 4096 pairs (l, m)
    int lq = pair >> 6, mk = pair & 63;
    float d0 = (float)((lq >> 3) - (mk >> 3));
    float d1 = (float)((lq & 7) - (mk & 7));
    float v0 = d0 * (8.0f / 7.0f);
    float v1 = d1 * (8.0f / 7.0f);
    float s0 = (v0 > 0.f) ? 1.f : ((v0 < 0.f) ? -1.f : 0.f);
    float s1 = (v1 > 0.f) ? 1.f : ((v1 < 0.f) ? -1.f : 0.f);
    float r0 = s0 * log2f(fabsf(v0) + 1.0f) * (1.0f / 3.0f);
    float r1 = s1 * log2f(fabsf(v1) + 1.0f) * (1.0f / 3.0f);
    float acc[8] = {0.f, 0.f, 0.f, 0.f, 0.f, 0.f, 0.f, 0.f};
    #pragma unroll 4
    for (int j = 0; j < 512; ++j) {
      float h = fmaxf(r0 * w1[j] + r1 * w1[512 + j] + b1[j], 0.0f);
      #pragma unroll
      for (int q = 0; q < 8; ++q) acc[q] += h * w2[j * 8 + q];
    }
    #pragma unroll
    for (int q = 0; q < 8; ++q) {
      float s = 16.0f / (1.0f + __expf(-acc[q]));
      cpbias[(q * 64 + lq) * 64 + mk] = s;
    }
  }
}

// ---------------------------------------------------------------------------
__device__ __forceinline__ int win_region(int tok, int wi, int wj) {
  int r = tok >> 3, cc = tok & 7;
  int rh = (wi == 15) ? ((r < 4) ? 1 : 2) : 0;
  int rw = (wj == 15) ? ((cc < 4) ? 1 : 2) : 0;
  return rh * 3 + rw;
}

// ---------------------------------------------------------------------------
// Fused qkv-projection + windowed cosine attention (R4 structure, 267 µs)
// + T5 setprio around the MFMA clusters: after the two staging barriers the
// 8 waves run desynced through qkv/QK/softmax/PV (attn-like regime where
// setprio measured +4-7%; not the lockstep-GEMM null case).
// ---------------------------------------------------------------------------
__global__ __launch_bounds__(512, 2) void fused_kernel(
    const float* __restrict__ x, const __bf16* __restrict__ W2,
    const float* __restrict__ bcat, const float* __restrict__ scale,
    const float* __restrict__ cpb, __bf16* __restrict__ out)
{
  __shared__ __align__(16) __bf16 xs[64 * 256];      // 32 KB
  __shared__ __align__(16) __bf16 qkp[8][64 * 72];   // 72 KB q/k stage -> P
  __shared__ __align__(16) __bf16 vst[8][64 * 36];   // 36 KB V [tok][unit]
  const f32x4 zz = {0.f, 0.f, 0.f, 0.f};

  int t = threadIdx.x;
  int h = t >> 6, l = t & 63, g = l >> 4, c = l & 15;
  int win = blockIdx.x, b = blockIdx.y;
  int wi = win >> 4, wj = win & 15;
  bool edge = (wi == 15) || (wj == 15);

  // ---- stage x tile (cyclic shift folded into source address) ----
  {
    int r = t >> 3;                      // local token 0..63
    int q8 = t & 7;                      // 32-float chunk of the 256 channels
    int ht = (wi * 8 + (r >> 3) + 4) & 127;
    int wt = (wj * 8 + (r & 7) + 4) & 127;
    const float* src = x + (size_t)((b * 128 + ht) * 128 + wt) * 256 + q8 * 32;
    #pragma unroll
    for (int q = 0; q < 4; ++q) {
      f32x4 a0 = *(const f32x4*)(src + q * 8);
      f32x4 a1 = *(const f32x4*)(src + q * 8 + 4);
      bf16x8 v;
      #pragma unroll
      for (int j = 0; j < 4; ++j) { v[j] = (__bf16)a0[j]; v[4 + j] = (__bf16)a1[j]; }
      int phys = (q8 * 4 + q) ^ (r & 7);
      *(bf16x8*)&xs[r * 256 + phys * 8] = v;
    }
  }
  __syncthreads();

  int toko[4];
  #pragma unroll
  for (int i = 0; i < 4; ++i) {
    int tok = 16 * i + c;
    int ht = (wi * 8 + (tok >> 3) + 4) & 127;
    int wt = (wj * 8 + (tok & 7) + 4) & 127;
    toko[i] = ((b * 128 + ht) * 128 + wt) * 256;
  }

  // ---- per-head qkv GEMM: acc[ft][tt] = C[ft*16+4g..+3][tt*16+c] ----
  f32x4 acc[6][4];
  #pragma unroll
  for (int ft = 0; ft < 6; ++ft)
    #pragma unroll
    for (int tt = 0; tt < 4; ++tt) acc[ft][tt] = zz;

  const __bf16* Wh = W2 + (size_t)h * 24576;
  #pragma unroll
  for (int ks = 0; ks < 8; ++ks) {
    bf16x8 wf[6], xf[4];
    #pragma unroll
    for (int ft = 0; ft < 6; ++ft)
      wf[ft] = *(const bf16x8*)(Wh + (size_t)((ft * 8 + ks) * 64 + l) * 8);
    #pragma unroll
    for (int tt = 0; tt < 4; ++tt) {
      int phys = (ks * 4 + g) ^ (c & 7);
      xf[tt] = *(const bf16x8*)&xs[(tt * 16 + c) * 256 + phys * 8];
    }
    __builtin_amdgcn_s_setprio(1);
    #pragma unroll
    for (int ft = 0; ft < 6; ++ft)
      #pragma unroll
      for (int tt = 0; tt < 4; ++tt)
        acc[ft][tt] = __builtin_amdgcn_mfma_f32_16x16x32_bf16(wf[ft], xf[tt], acc[ft][tt], 0, 0, 0);
    __builtin_amdgcn_s_setprio(0);
  }

  // ---- bias add (concat layout, col = h*96 + ft*16 + 4g + i) ----
  #pragma unroll
  for (int ft = 0; ft < 6; ++ft) {
    f32x4 bb = *(const f32x4*)&bcat[h * 96 + ft * 16 + 4 * g];
    #pragma unroll
    for (int tt = 0; tt < 4; ++tt) acc[ft][tt] += bb;
  }

  float ls = __expf(fminf(scale[h], 4.6051701859880914f));  // ln(100)

  // ---- l2-normalize q (ft 0,1) and k (ft 2,3); stage q,k,v to LDS ----
  #pragma unroll
  for (int tt = 0; tt < 4; ++tt) {
    float sq = 0.f, sk = 0.f;
    #pragma unroll
    for (int i = 0; i < 4; ++i) {
      sq += acc[0][tt][i] * acc[0][tt][i] + acc[1][tt][i] * acc[1][tt][i];
      sk += acc[2][tt][i] * acc[2][tt][i] + acc[3][tt][i] * acc[3][tt][i];
    }
    sq += __shfl_xor(sq, 16); sq += __shfl_xor(sq, 32);
    sk += __shfl_xor(sk, 16); sk += __shfl_xor(sk, 32);
    float rq = rsqrtf(fmaxf(sq, 1.55e-5f)) * ls;
    float rk = rsqrtf(fmaxf(sk, 1.55e-5f));
    __bf16* row = &qkp[h][(tt * 16 + c) * 72];
    bf16x4 w0, w1, w2, w3, v0, v1;
    #pragma unroll
    for (int i = 0; i < 4; ++i) {
      w0[i] = (__bf16)(acc[0][tt][i] * rq);
      w1[i] = (__bf16)(acc[1][tt][i] * rq);
      w2[i] = (__bf16)(acc[2][tt][i] * rk);
      w3[i] = (__bf16)(acc[3][tt][i] * rk);
      v0[i] = (__bf16)acc[4][tt][i];
      v1[i] = (__bf16)acc[5][tt][i];
    }
    *(bf16x4*)&row[4 * g]      = w0;   // q units 4g..
    *(bf16x4*)&row[16 + 4 * g] = w1;   // q units 16+4g..
    *(bf16x4*)&row[32 + 4 * g] = w2;   // k units 4g..
    *(bf16x4*)&row[48 + 4 * g] = w3;   // k units 16+4g..
    __bf16* vrow = &vst[h][(tt * 16 + c) * 36];
    *(bf16x4*)&vrow[4 * g]      = v0;
    *(bf16x4*)&vrow[16 + 4 * g] = v1;
  }

  // ---- fetch Q/K MFMA fragments (wave-private LDS, compiler orders) ----
  bf16x8 kf[4], qf[4];
  #pragma unroll
  for (int i = 0; i < 4; ++i) {
    kf[i] = *(const bf16x8*)&qkp[h][(16 * i + c) * 72 + 32 + 8 * g];
    qf[i] = *(const bf16x8*)&qkp[h][(16 * i + c) * 72 + 8 * g];
  }

  // ---- QK^T + softmax; P^T overwrites the dead q/k stage ----
  float rsum[4];
  __bf16* Pw = &qkp[h][0];
  #pragma unroll
  for (int nt = 0; nt < 4; ++nt) {
    f32x4 tt4[4];
    __builtin_amdgcn_s_setprio(1);
    #pragma unroll
    for (int mt = 0; mt < 4; ++mt)
      tt4[mt] = __builtin_amdgcn_mfma_f32_16x16x32_bf16(kf[mt], qf[nt], zz, 0, 0, 0);
    __builtin_amdgcn_s_setprio(0);
    int q = nt * 16 + c;
    float p[16];
    #pragma unroll
    for (int mt = 0; mt < 4; ++mt) {
      f32x4 bb = *(const f32x4*)&cpb[(h * 64 + q) * 64 + mt * 16 + 4 * g];
      #pragma unroll
      for (int i = 0; i < 4; ++i) p[mt * 4 + i] = tt4[mt][i] + bb[i];
    }
    if (edge) {
      int regq = win_region(q, wi, wj);
      #pragma unroll
      for (int mt = 0; mt < 4; ++mt)
        #pragma unroll
        for (int i = 0; i < 4; ++i) {
          int k = mt * 16 + 4 * g + i;
          if (win_region(k, wi, wj) != regq) p[mt * 4 + i] -= 100.0f;
        }
    }
    float mx = -1e30f;
    #pragma unroll
    for (int j = 0; j < 16; ++j) mx = fmaxf(mx, p[j]);
    mx = fmaxf(mx, __shfl_xor(mx, 16));
    mx = fmaxf(mx, __shfl_xor(mx, 32));
    float sum = 0.f;
    #pragma unroll
    for (int j = 0; j < 16; ++j) { p[j] = __expf(p[j] - mx); sum += p[j]; }
    sum += __shfl_xor(sum, 16); sum += __shfl_xor(sum, 32);
    rsum[nt] = sum;
    #pragma unroll
    for (int mt = 0; mt < 4; ++mt) {
      bf16x4 px = { (__bf16)p[mt * 4 + 0], (__bf16)p[mt * 4 + 1],
                    (__bf16)p[mt * 4 + 2], (__bf16)p[mt * 4 + 3] };
      *(bf16x4*)&Pw[q * 72 + mt * 16 + 4 * g] = px;
    }
  }

  // ---- O^T = V^T @ P^T ----
  #pragma unroll
  for (int mh = 0; mh < 2; ++mh) {
    f32x4 oacc[4];
    #pragma unroll
    for (int nt = 0; nt < 4; ++nt) oacc[nt] = zz;
    #pragma unroll
    for (int ks = 0; ks < 2; ++ks) {
      bf16x8 va;
      #pragma unroll
      for (int j = 0; j < 8; ++j)
        va[j] = vst[h][(32 * ks + 8 * g + j) * 36 + 16 * mh + c];
      __builtin_amdgcn_s_setprio(1);
      #pragma unroll
      for (int nt = 0; nt < 4; ++nt) {
        bf16x8 pfr = *(const bf16x8*)&Pw[(nt * 16 + c) * 72 + 32 * ks + 8 * g];
        oacc[nt] = __builtin_amdgcn_mfma_f32_16x16x32_bf16(va, pfr, oacc[nt], 0, 0, 0);
      }
      __builtin_amdgcn_s_setprio(0);
    }
    #pragma unroll
    for (int nt = 0; nt < 4; ++nt) {
      float rinv = 1.0f / rsum[nt];
      bf16x4 ov = { (__bf16)(oacc[nt][0] * rinv), (__bf16)(oacc[nt][1] * rinv),
                    (__bf16)(oacc[nt][2] * rinv), (__bf16)(oacc[nt][3] * rinv) };
      *(bf16x4*)(out + toko[nt] + h * 32 + 16 * mh + 4 * g) = ov;
    }
  }
}

// ---------------------------------------------------------------------------
// proj2: A-stationary output projection with COALESCED f32 output.
// Block = 128 tokens, 512 threads = 8 waves, wave = 32-oc group.
// A tile staged once in LDS (chunk-XOR swizzle); 128 MFMA/wave from packed
// L2-resident Wp. Epilogue: results staged through LDS (aliasing the dead
// A-tile buffer, padded row stride 260 f32) in two 64-token halves, then
// copied out as full 1-KB contiguous rows (8 lanes x 128 B) -> no
// partial-line RMW on the 268 MB f32 output.
// ---------------------------------------------------------------------------
__global__ __launch_bounds__(512, 4) void proj2_kernel(
    const __bf16* __restrict__ A, const __bf16* __restrict__ Wp,
    const float* __restrict__ pb, float* __restrict__ outf)
{
  __shared__ __align__(16) char pbuf[64 * 260 * 4];   // 66.56 KB (>= 64 KB)
  __bf16* os = (__bf16*)pbuf;                         // A tile [128][256] bf16
  float*  osF = (float*)pbuf;                         // result [64][260] f32
  const f32x4 zz = {0.f, 0.f, 0.f, 0.f};
  int t = threadIdx.x;
  int wv = t >> 6, l = t & 63, g = l >> 4, c = l & 15;
  int mblk = blockIdx.x;                 // 2048 blocks x 128 tokens

  // ---- stage A tile (chunk-XOR swizzle, rows keep low-3-bit identity) ----
  {
    int r = t >> 2;                      // row 0..127
    int q4 = t & 3;                      // quarter of the 256 channels
    const __bf16* src = A + (size_t)(mblk * 128 + r) * 256 + q4 * 64;
    #pragma unroll
    for (int q = 0; q < 8; ++q) {
      bf16x8 v = *(const bf16x8*)(src + q * 8);
      int phys = (q4 * 8 + q) ^ (r & 7);
      *(bf16x8*)&os[r * 256 + phys * 8] = v;
    }
  }
  __syncthreads();

  f32x4 acc[2][8];
  #pragma unroll
  for (int ft = 0; ft < 2; ++ft)
    #pragma unroll
    for (int tt = 0; tt < 8; ++tt) acc[ft][tt] = zz;

  const __bf16* Wph = Wp + (size_t)wv * 8192;
  #pragma unroll
  for (int ks = 0; ks < 8; ++ks) {
    bf16x8 w0 = *(const bf16x8*)(Wph + (size_t)((0 * 8 + ks) * 64 + l) * 8);
    bf16x8 w1 = *(const bf16x8*)(Wph + (size_t)((1 * 8 + ks) * 64 + l) * 8);
    #pragma unroll
    for (int tt = 0; tt < 8; ++tt) {
      int phys = (ks * 4 + g) ^ (c & 7);
      bf16x8 xf = *(const bf16x8*)&os[(tt * 16 + c) * 256 + phys * 8];
      acc[0][tt] = __builtin_amdgcn_mfma_f32_16x16x32_bf16(w0, xf, acc[0][tt], 0, 0, 0);
      acc[1][tt] = __builtin_amdgcn_mfma_f32_16x16x32_bf16(w1, xf, acc[1][tt], 0, 0, 0);
    }
  }

  f32x4 bb0 = *(const f32x4*)&pb[wv * 32 + 4 * g];
  f32x4 bb1 = *(const f32x4*)&pb[wv * 32 + 16 + 4 * g];

  // ---- epilogue: two 64-token halves via LDS transpose, coalesced out ----
  #pragma unroll
  for (int half = 0; half < 2; ++half) {
    __syncthreads();   // A-tile reads (half 0) / prior copy-out (half 1) done
    #pragma unroll
    for (int ntl = 0; ntl < 4; ++ntl) {
      int tt = half * 4 + ntl;
      *(f32x4*)&osF[(ntl * 16 + c) * 260 + wv * 32 + 4 * g]      = acc[0][tt] + bb0;
      *(f32x4*)&osF[(ntl * 16 + c) * 260 + wv * 32 + 16 + 4 * g] = acc[1][tt] + bb1;
    }
    __syncthreads();
    {
      int r = t >> 3;                    // row 0..63
      int chunk = t & 7;                 // 8 chunks of 32 floats
      const float* src = &osF[r * 260 + chunk * 32];
      float* dst = &outf[(size_t)(mblk * 128 + half * 64 + r) * 256 + chunk * 32];
      #pragma unroll
      for (int i = 0; i < 8; ++i)
        *(f32x4*)&dst[4 * i] = *(const f32x4*)&src[4 * i];
    }
  }
}

// ---------------------------------------------------------------------------
extern "C" void kernel_launch(void* const* d_in, const int* in_sizes, int n_in,
                              void* d_out, int out_size, void* d_ws, size_t ws_size,
                              hipStream_t stream)
{
  const float* x      = (const float*)d_in[0];
  const float* qkv_w  = (const float*)d_in[1];
  const float* q_bias = (const float*)d_in[2];
  const float* v_bias = (const float*)d_in[3];
  const float* scale  = (const float*)d_in[4];
  const float* cpb_w1 = (const float*)d_in[5];
  const float* cpb_b1 = (const float*)d_in[6];
  const float* cpb_w2 = (const float*)d_in[7];
  const float* proj_w = (const float*)d_in[8];
  const float* proj_b = (const float*)d_in[9];

  char* ws = (char*)d_ws;
  // layout (bytes):
  //   [0, 134217728)           attn-out bf16 [262144][256]
  //   [134217728, 134610944)   W2 bf16 packed qkv weights
  //   [134610944, 134742016)   Wp bf16 packed proj weights
  //   [134742016, 134745088)   bcat f32[768]
  //   [134745088, 134876160)   cpb bias f32 [8][64][64]
  __bf16* aout = (__bf16*)(ws);
  __bf16* W2   = (__bf16*)(ws + 134217728LL);
  __bf16* Wp   = (__bf16*)(ws + 134610944LL);
  float*  bcat = (float*) (ws + 134742016LL);
  float*  cpb  = (float*) (ws + 134745088LL);

  prep_kernel<<<147, 256, 0, stream>>>(qkv_w, proj_w, q_bias, v_bias,
                                       cpb_w1, cpb_b1, cpb_w2, W2, Wp, bcat, cpb);
  fused_kernel<<<dim3(256, 16), 512, 0, stream>>>(x, W2, bcat, scale, cpb, aout);
  proj2_kernel<<<2048, 512, 0, stream>>>(aout, Wp, proj_b, (float*)d_out);
}

// Round 17
// 384.218 us; speedup vs baseline: 1.1386x; 1.1386x over previous
//
#include <hip/hip_runtime.h>

typedef __attribute__((ext_vector_type(4))) float  f32x4;
typedef __attribute__((ext_vector_type(8))) __bf16 bf16x8;
typedef __attribute__((ext_vector_type(4))) __bf16 bf16x4;

// ---------------------------------------------------------------------------
// prep: weight packing + bias concat + CPB table, one launch (147 blocks).
// Blocks [0,131): i = bid*256+tid covers
//   [0, 24576)        W2 packed qkv weights (head, ft, ks, lane fragment order)
//   [24576, 32768)    Wp packed proj weights (oc-group, ft, ks, lane)
//   [32768, 33536)    bcat = concat(q_bias, 0, v_bias) f32[768]
// Blocks [131, 147): CPB table cpbias[8][64][64] f32 (4096 (l,m) pairs)
// ---------------------------------------------------------------------------
__global__ __launch_bounds__(256) void prep_kernel(
    const float* __restrict__ qw, const float* __restrict__ pw,
    const float* __restrict__ qb, const float* __restrict__ vb,
    const float* __restrict__ w1, const float* __restrict__ b1,
    const float* __restrict__ w2,
    __bf16* __restrict__ W2, __bf16* __restrict__ Wp,
    float* __restrict__ bcat, float* __restrict__ cpbias)
{
  if (blockIdx.x < 131) {
    int i = blockIdx.x * 256 + threadIdx.x;
    if (i < 24576) {                       // 8 heads * 6 ft * 8 ks * 64 lanes
      int h = i / 3072, rem = i - h * 3072;
      int ft = rem >> 9, rem2 = rem & 511;
      int ks = rem2 >> 6, l = rem2 & 63;
      int g = l >> 4, c = l & 15;
      int col = h * 96 + ft * 16 + c;
      bf16x8 v;
      #pragma unroll
      for (int j = 0; j < 8; ++j)
        v[j] = (__bf16)qw[(ks * 32 + g * 8 + j) * 768 + col];
      *(bf16x8*)(W2 + (size_t)i * 8) = v;
    } else if (i < 24576 + 8192) {         // 8 oc-groups * 2 ft * 8 ks * 64 lanes
      int j = i - 24576;
      int wv = j >> 10, rem = j & 1023;
      int ft = rem >> 9, rem2 = rem & 511;
      int ks = rem2 >> 6, l = rem2 & 63;
      int g = l >> 4, c = l & 15;
      int col = wv * 32 + ft * 16 + c;
      bf16x8 v;
      #pragma unroll
      for (int j8 = 0; j8 < 8; ++j8)
        v[j8] = (__bf16)pw[(ks * 32 + g * 8 + j8) * 256 + col];
      *(bf16x8*)(Wp + (size_t)j * 8) = v;
    } else if (i < 24576 + 8192 + 768) {
      int cdx = i - 24576 - 8192;
      bcat[cdx] = (cdx < 256) ? qb[cdx] : ((cdx < 512) ? 0.0f : vb[cdx - 512]);
    }
  } else {
    int pair = (blockIdx.x - 131) * 256 + threadIdx.x;   // 4096 pairs (l, m)
    int lq = pair >> 6, mk = pair & 63;
    float d0 = (float)((lq >> 3) - (mk >> 3));
    float d1 = (float)((lq & 7) - (mk & 7));
    float v0 = d0 * (8.0f / 7.0f);
    float v1 = d1 * (8.0f / 7.0f);
    float s0 = (v0 > 0.f) ? 1.f : ((v0 < 0.f) ? -1.f : 0.f);
    float s1 = (v1 > 0.f) ? 1.f : ((v1 < 0.f) ? -1.f : 0.f);
    float r0 = s0 * log2f(fabsf(v0) + 1.0f) * (1.0f / 3.0f);
    float r1 = s1 * log2f(fabsf(v1) + 1.0f) * (1.0f / 3.0f);
    float acc[8] = {0.f, 0.f, 0.f, 0.f, 0.f, 0.f, 0.f, 0.f};
    #pragma unroll 4
    for (int j = 0; j < 512; ++j) {
      float h = fmaxf(r0 * w1[j] + r1 * w1[512 + j] + b1[j], 0.0f);
      #pragma unroll
      for (int q = 0; q < 8; ++q) acc[q] += h * w2[j * 8 + q];
    }
    #pragma unroll
    for (int q = 0; q < 8; ++q) {
      float s = 16.0f / (1.0f + __expf(-acc[q]));
      cpbias[(q * 64 + lq) * 64 + mk] = s;
    }
  }
}

// ---------------------------------------------------------------------------
__device__ __forceinline__ int win_region(int tok, int wi, int wj) {
  int r = tok >> 3, cc = tok & 7;
  int rh = (wi == 15) ? ((r < 4) ? 1 : 2) : 0;
  int rw = (wj == 15) ? ((cc < 4) ? 1 : 2) : 0;
  return rh * 3 + rw;
}

// ---------------------------------------------------------------------------
// Fused qkv-projection + windowed cosine attention (R4 structure + T5
// setprio, measured 261 µs). Block = (window, batch), 512 threads = 8 waves,
// wave = head.
// ---------------------------------------------------------------------------
__global__ __launch_bounds__(512, 2) void fused_kernel(
    const float* __restrict__ x, const __bf16* __restrict__ W2,
    const float* __restrict__ bcat, const float* __restrict__ scale,
    const float* __restrict__ cpb, __bf16* __restrict__ out)
{
  __shared__ __align__(16) __bf16 xs[64 * 256];      // 32 KB
  __shared__ __align__(16) __bf16 qkp[8][64 * 72];   // 72 KB q/k stage -> P
  __shared__ __align__(16) __bf16 vst[8][64 * 36];   // 36 KB V [tok][unit]
  const f32x4 zz = {0.f, 0.f, 0.f, 0.f};

  int t = threadIdx.x;
  int h = t >> 6, l = t & 63, g = l >> 4, c = l & 15;
  int win = blockIdx.x, b = blockIdx.y;
  int wi = win >> 4, wj = win & 15;
  bool edge = (wi == 15) || (wj == 15);

  // ---- stage x tile (cyclic shift folded into source address) ----
  {
    int r = t >> 3;                      // local token 0..63
    int q8 = t & 7;                      // 32-float chunk of the 256 channels
    int ht = (wi * 8 + (r >> 3) + 4) & 127;
    int wt = (wj * 8 + (r & 7) + 4) & 127;
    const float* src = x + (size_t)((b * 128 + ht) * 128 + wt) * 256 + q8 * 32;
    #pragma unroll
    for (int q = 0; q < 4; ++q) {
      f32x4 a0 = *(const f32x4*)(src + q * 8);
      f32x4 a1 = *(const f32x4*)(src + q * 8 + 4);
      bf16x8 v;
      #pragma unroll
      for (int j = 0; j < 4; ++j) { v[j] = (__bf16)a0[j]; v[4 + j] = (__bf16)a1[j]; }
      int phys = (q8 * 4 + q) ^ (r & 7);
      *(bf16x8*)&xs[r * 256 + phys * 8] = v;
    }
  }
  __syncthreads();

  int toko[4];
  #pragma unroll
  for (int i = 0; i < 4; ++i) {
    int tok = 16 * i + c;
    int ht = (wi * 8 + (tok >> 3) + 4) & 127;
    int wt = (wj * 8 + (tok & 7) + 4) & 127;
    toko[i] = ((b * 128 + ht) * 128 + wt) * 256;
  }

  // ---- per-head qkv GEMM: acc[ft][tt] = C[ft*16+4g..+3][tt*16+c] ----
  f32x4 acc[6][4];
  #pragma unroll
  for (int ft = 0; ft < 6; ++ft)
    #pragma unroll
    for (int tt = 0; tt < 4; ++tt) acc[ft][tt] = zz;

  const __bf16* Wh = W2 + (size_t)h * 24576;
  #pragma unroll
  for (int ks = 0; ks < 8; ++ks) {
    bf16x8 wf[6], xf[4];
    #pragma unroll
    for (int ft = 0; ft < 6; ++ft)
      wf[ft] = *(const bf16x8*)(Wh + (size_t)((ft * 8 + ks) * 64 + l) * 8);
    #pragma unroll
    for (int tt = 0; tt < 4; ++tt) {
      int phys = (ks * 4 + g) ^ (c & 7);
      xf[tt] = *(const bf16x8*)&xs[(tt * 16 + c) * 256 + phys * 8];
    }
    __builtin_amdgcn_s_setprio(1);
    #pragma unroll
    for (int ft = 0; ft < 6; ++ft)
      #pragma unroll
      for (int tt = 0; tt < 4; ++tt)
        acc[ft][tt] = __builtin_amdgcn_mfma_f32_16x16x32_bf16(wf[ft], xf[tt], acc[ft][tt], 0, 0, 0);
    __builtin_amdgcn_s_setprio(0);
  }

  // ---- bias add (concat layout, col = h*96 + ft*16 + 4g + i) ----
  #pragma unroll
  for (int ft = 0; ft < 6; ++ft) {
    f32x4 bb = *(const f32x4*)&bcat[h * 96 + ft * 16 + 4 * g];
    #pragma unroll
    for (int tt = 0; tt < 4; ++tt) acc[ft][tt] += bb;
  }

  float ls = __expf(fminf(scale[h], 4.6051701859880914f));  // ln(100)

  // ---- l2-normalize q (ft 0,1) and k (ft 2,3); stage q,k,v to LDS ----
  #pragma unroll
  for (int tt = 0; tt < 4; ++tt) {
    float sq = 0.f, sk = 0.f;
    #pragma unroll
    for (int i = 0; i < 4; ++i) {
      sq += acc[0][tt][i] * acc[0][tt][i] + acc[1][tt][i] * acc[1][tt][i];
      sk += acc[2][tt][i] * acc[2][tt][i] + acc[3][tt][i] * acc[3][tt][i];
    }
    sq += __shfl_xor(sq, 16); sq += __shfl_xor(sq, 32);
    sk += __shfl_xor(sk, 16); sk += __shfl_xor(sk, 32);
    float rq = rsqrtf(fmaxf(sq, 1.55e-5f)) * ls;
    float rk = rsqrtf(fmaxf(sk, 1.55e-5f));
    __bf16* row = &qkp[h][(tt * 16 + c) * 72];
    bf16x4 w0, w1, w2, w3, v0, v1;
    #pragma unroll
    for (int i = 0; i < 4; ++i) {
      w0[i] = (__bf16)(acc[0][tt][i] * rq);
      w1[i] = (__bf16)(acc[1][tt][i] * rq);
      w2[i] = (__bf16)(acc[2][tt][i] * rk);
      w3[i] = (__bf16)(acc[3][tt][i] * rk);
      v0[i] = (__bf16)acc[4][tt][i];
      v1[i] = (__bf16)acc[5][tt][i];
    }
    *(bf16x4*)&row[4 * g]      = w0;   // q units 4g..
    *(bf16x4*)&row[16 + 4 * g] = w1;   // q units 16+4g..
    *(bf16x4*)&row[32 + 4 * g] = w2;   // k units 4g..
    *(bf16x4*)&row[48 + 4 * g] = w3;   // k units 16+4g..
    __bf16* vrow = &vst[h][(tt * 16 + c) * 36];
    *(bf16x4*)&vrow[4 * g]      = v0;
    *(bf16x4*)&vrow[16 + 4 * g] = v1;
  }

  // ---- fetch Q/K MFMA fragments (wave-private LDS, compiler orders) ----
  bf16x8 kf[4], qf[4];
  #pragma unroll
  for (int i = 0; i < 4; ++i) {
    kf[i] = *(const bf16x8*)&qkp[h][(16 * i + c) * 72 + 32 + 8 * g];
    qf[i] = *(const bf16x8*)&qkp[h][(16 * i + c) * 72 + 8 * g];
  }

  // ---- QK^T + softmax; P^T overwrites the dead q/k stage ----
  float rsum[4];
  __bf16* Pw = &qkp[h][0];
  #pragma unroll
  for (int nt = 0; nt < 4; ++nt) {
    f32x4 tt4[4];
    __builtin_amdgcn_s_setprio(1);
    #pragma unroll
    for (int mt = 0; mt < 4; ++mt)
      tt4[mt] = __builtin_amdgcn_mfma_f32_16x16x32_bf16(kf[mt], qf[nt], zz, 0, 0, 0);
    __builtin_amdgcn_s_setprio(0);
    int q = nt * 16 + c;
    float p[16];
    #pragma unroll
    for (int mt = 0; mt < 4; ++mt) {
      f32x4 bb = *(const f32x4*)&cpb[(h * 64 + q) * 64 + mt * 16 + 4 * g];
      #pragma unroll
      for (int i = 0; i < 4; ++i) p[mt * 4 + i] = tt4[mt][i] + bb[i];
    }
    if (edge) {
      int regq = win_region(q, wi, wj);
      #pragma unroll
      for (int mt = 0; mt < 4; ++mt)
        #pragma unroll
        for (int i = 0; i < 4; ++i) {
          int k = mt * 16 + 4 * g + i;
          if (win_region(k, wi, wj) != regq) p[mt * 4 + i] -= 100.0f;
        }
    }
    float mx = -1e30f;
    #pragma unroll
    for (int j = 0; j < 16; ++j) mx = fmaxf(mx, p[j]);
    mx = fmaxf(mx, __shfl_xor(mx, 16));
    mx = fmaxf(mx, __shfl_xor(mx, 32));
    float sum = 0.f;
    #pragma unroll
    for (int j = 0; j < 16; ++j) { p[j] = __expf(p[j] - mx); sum += p[j]; }
    sum += __shfl_xor(sum, 16); sum += __shfl_xor(sum, 32);
    rsum[nt] = sum;
    #pragma unroll
    for (int mt = 0; mt < 4; ++mt) {
      bf16x4 px = { (__bf16)p[mt * 4 + 0], (__bf16)p[mt * 4 + 1],
                    (__bf16)p[mt * 4 + 2], (__bf16)p[mt * 4 + 3] };
      *(bf16x4*)&Pw[q * 72 + mt * 16 + 4 * g] = px;
    }
  }

  // ---- O^T = V^T @ P^T ----
  #pragma unroll
  for (int mh = 0; mh < 2; ++mh) {
    f32x4 oacc[4];
    #pragma unroll
    for (int nt = 0; nt < 4; ++nt) oacc[nt] = zz;
    #pragma unroll
    for (int ks = 0; ks < 2; ++ks) {
      bf16x8 va;
      #pragma unroll
      for (int j = 0; j < 8; ++j)
        va[j] = vst[h][(32 * ks + 8 * g + j) * 36 + 16 * mh + c];
      __builtin_amdgcn_s_setprio(1);
      #pragma unroll
      for (int nt = 0; nt < 4; ++nt) {
        bf16x8 pfr = *(const bf16x8*)&Pw[(nt * 16 + c) * 72 + 32 * ks + 8 * g];
        oacc[nt] = __builtin_amdgcn_mfma_f32_16x16x32_bf16(va, pfr, oacc[nt], 0, 0, 0);
      }
      __builtin_amdgcn_s_setprio(0);
    }
    #pragma unroll
    for (int nt = 0; nt < 4; ++nt) {
      float rinv = 1.0f / rsum[nt];
      bf16x4 ov = { (__bf16)(oacc[nt][0] * rinv), (__bf16)(oacc[nt][1] * rinv),
                    (__bf16)(oacc[nt][2] * rinv), (__bf16)(oacc[nt][3] * rinv) };
      *(bf16x4*)(out + toko[nt] + h * 32 + 16 * mh + 4 * g) = ov;
    }
  }
}

// ---------------------------------------------------------------------------
// proj2: A-stationary output projection, 64-token blocks for 4 blocks/CU.
// 512 threads = 8 waves, wave = 32-oc group; A tile (64x256 bf16 = 32 KB)
// staged once (single barrier); 64 MFMA/wave from packed L2-resident Wp;
// direct f32x4 stores (line-complete per (wv,ft) pair — verified R16).
// 4096 blocks; low regs (32 acc) + 32 KB LDS -> 4 co-resident blocks/CU
// hide HBM load/store latency for this short streaming kernel.
// ---------------------------------------------------------------------------
__global__ __launch_bounds__(512, 4) void proj2_kernel(
    const __bf16* __restrict__ A, const __bf16* __restrict__ Wp,
    const float* __restrict__ pb, float* __restrict__ outf)
{
  __shared__ __align__(16) __bf16 os[64 * 256];   // 32 KB
  const f32x4 zz = {0.f, 0.f, 0.f, 0.f};
  int t = threadIdx.x;
  int wv = t >> 6, l = t & 63, g = l >> 4, c = l & 15;
  int mblk = blockIdx.x;                 // 4096 blocks x 64 tokens

  // ---- stage A tile (chunk-XOR swizzle, rows keep low-3-bit identity) ----
  {
    int r = t >> 3;                      // row 0..63
    int q8 = t & 7;                      // 32-bf16 chunk of the 256 channels
    const __bf16* src = A + (size_t)(mblk * 64 + r) * 256 + q8 * 32;
    #pragma unroll
    for (int q = 0; q < 4; ++q) {
      bf16x8 v = *(const bf16x8*)(src + q * 8);
      int phys = (q8 * 4 + q) ^ (r & 7);
      *(bf16x8*)&os[r * 256 + phys * 8] = v;
    }
  }
  __syncthreads();

  f32x4 acc[2][4];
  #pragma unroll
  for (int ft = 0; ft < 2; ++ft)
    #pragma unroll
    for (int tt = 0; tt < 4; ++tt) acc[ft][tt] = zz;

  const __bf16* Wph = Wp + (size_t)wv * 8192;
  #pragma unroll
  for (int ks = 0; ks < 8; ++ks) {
    bf16x8 w0 = *(const bf16x8*)(Wph + (size_t)((0 * 8 + ks) * 64 + l) * 8);
    bf16x8 w1 = *(const bf16x8*)(Wph + (size_t)((1 * 8 + ks) * 64 + l) * 8);
    #pragma unroll
    for (int tt = 0; tt < 4; ++tt) {
      int phys = (ks * 4 + g) ^ (c & 7);
      bf16x8 xf = *(const bf16x8*)&os[(tt * 16 + c) * 256 + phys * 8];
      acc[0][tt] = __builtin_amdgcn_mfma_f32_16x16x32_bf16(w0, xf, acc[0][tt], 0, 0, 0);
      acc[1][tt] = __builtin_amdgcn_mfma_f32_16x16x32_bf16(w1, xf, acc[1][tt], 0, 0, 0);
    }
  }

  #pragma unroll
  for (int ft = 0; ft < 2; ++ft) {
    f32x4 bb = *(const f32x4*)&pb[wv * 32 + ft * 16 + 4 * g];
    #pragma unroll
    for (int tt = 0; tt < 4; ++tt) {
      f32x4 res = acc[ft][tt] + bb;
      *(f32x4*)&outf[(size_t)(mblk * 64 + tt * 16 + c) * 256 + wv * 32 + ft * 16 + 4 * g] = res;
    }
  }
}

// ---------------------------------------------------------------------------
extern "C" void kernel_launch(void* const* d_in, const int* in_sizes, int n_in,
                              void* d_out, int out_size, void* d_ws, size_t ws_size,
                              hipStream_t stream)
{
  const float* x      = (const float*)d_in[0];
  const float* qkv_w  = (const float*)d_in[1];
  const float* q_bias = (const float*)d_in[2];
  const float* v_bias = (const float*)d_in[3];
  const float* scale  = (const float*)d_in[4];
  const float* cpb_w1 = (const float*)d_in[5];
  const float* cpb_b1 = (const float*)d_in[6];
  const float* cpb_w2 = (const float*)d_in[7];
  const float* proj_w = (const float*)d_in[8];
  const float* proj_b = (const float*)d_in[9];

  char* ws = (char*)d_ws;
  // layout (bytes):
  //   [0, 134217728)           attn-out bf16 [262144][256]
  //   [134217728, 134610944)   W2 bf16 packed qkv weights
  //   [134610944, 134742016)   Wp bf16 packed proj weights
  //   [134742016, 134745088)   bcat f32[768]
  //   [134745088, 134876160)   cpb bias f32 [8][64][64]
  __bf16* aout = (__bf16*)(ws);
  __bf16* W2   = (__bf16*)(ws + 134217728LL);
  __bf16* Wp   = (__bf16*)(ws + 134610944LL);
  float*  bcat = (float*) (ws + 134742016LL);
  float*  cpb  = (float*) (ws + 134745088LL);

  prep_kernel<<<147, 256, 0, stream>>>(qkv_w, proj_w, q_bias, v_bias,
                                       cpb_w1, cpb_b1, cpb_w2, W2, Wp, bcat, cpb);
  fused_kernel<<<dim3(256, 16), 512, 0, stream>>>(x, W2, bcat, scale, cpb, aout);
  proj2_kernel<<<4096, 512, 0, stream>>>(aout, Wp, proj_b, (float*)d_out);
}